// Round 1
// baseline (394.878 us; speedup 1.0000x reference)
//
#include <hip/hip_runtime.h>

#define K_ 9
#define SIGMA_INV 12.5f   // 1/0.08
#define EPS 1e-5f
#define B_ 4
#define C_ 64
#define O_ 64
#define N_ 16384
#define NT 128
#define XSP 68   // LDS row pitch (floats), 16B-aligned, conflict-friendly
#define WP  68

// K1: transpose input [B][C][N] -> xt [B][N][C]
__global__ __launch_bounds__(256) void k_transpose(const float* __restrict__ in,
                                                   float* __restrict__ xt) {
    __shared__ float tile[64][65];
    int b = blockIdx.y;
    int n0 = blockIdx.x * 64;
    int t = threadIdx.x;
    for (int rep = 0; rep < 16; ++rep) {
        int idx = rep * 256 + t;
        int c = idx >> 6, j = idx & 63;
        tile[c][j] = in[((size_t)b * C_ + c) * N_ + n0 + j];
    }
    __syncthreads();
    for (int rep = 0; rep < 16; ++rep) {
        int idx = rep * 256 + t;
        int j = idx >> 6, c = idx & 63;
        xt[((size_t)b * N_ + n0 + j) * C_ + c] = tile[c][j];
    }
}

// K2: compose gather chains. cidx[s][b][n] = (s==0) ? idx[b,n,0] : cidx[s-1][b, idx[b,n,s]]
__global__ void k_compose(const int* __restrict__ indices, int* __restrict__ cidx, int step) {
    int gid = blockIdx.x * blockDim.x + threadIdx.x;  // over B*N
    int b = gid / N_, n = gid - b * N_;
    int id = indices[((size_t)b * N_ + n) * 4 + step];
    int v;
    if (step == 0) v = id;
    else v = cidx[(size_t)(step - 1) * B_ * N_ + (size_t)b * N_ + id];
    cidx[(size_t)step * B_ * N_ + (size_t)b * N_ + n] = v;
}

// K3: weighted conv for all 4 orderings. Writes ybuf[i][b][n][o].
__global__ __launch_bounds__(256) void k_conv(
    const float* __restrict__ xt, const int* __restrict__ cidx,
    const float* __restrict__ mc, const float* __restrict__ cw,
    float* __restrict__ ybuf)
{
    __shared__ float xs[NT + 8][XSP];
    __shared__ float w4s[O_][WP];
    __shared__ float dws[8][NT];
    __shared__ float cs[3][NT + 8];
    int n0 = blockIdx.x * NT;
    int b  = blockIdx.y;
    int i  = blockIdx.z;
    int t  = threadIdx.x;
    const int* ci = cidx + (size_t)i * B_ * N_ + (size_t)b * N_;

    // stage x window [n0-4, n0+NT+4) gathered via composed indices (zero pad OOR)
    for (int idx = t; idx < (NT + 8) * 16; idx += 256) {
        int row = idx >> 4, c4 = idx & 15;
        int m = n0 + row - 4;
        float4 v = make_float4(0.f, 0.f, 0.f, 0.f);
        if (m >= 0 && m < N_) {
            int pos = ci[m];
            v = *(const float4*)&xt[((size_t)b * N_ + pos) * C_ + c4 * 4];
        }
        *(float4*)&xs[row][c4 * 4] = v;
    }
    // center-tap weights w4s[o][c] = cw[i][o][c][4]
    for (int idx = t; idx < O_ * C_; idx += 256) {
        int o = idx >> 6, c = idx & 63;
        w4s[o][c] = cw[((size_t)(i * O_ + o) * C_ + c) * K_ + 4];
    }
    // coords window (zeros OOR; unused there anyway since dw forced 0)
    for (int idx = t; idx < 3 * (NT + 8); idx += 256) {
        int a = idx / (NT + 8), r = idx - a * (NT + 8);
        int m = n0 + r - 4;
        cs[a][r] = (m >= 0 && m < N_) ? mc[(((size_t)b * 3 + a) * N_ + m) * 4 + i] : 0.f;
    }
    __syncthreads();
    // dw for the 8 non-center taps (center tap == 1 exactly)
    for (int idx = t; idx < 8 * NT; idx += 256) {
        int kk = idx >> 7, n = idx & (NT - 1);
        int k = kk + (kk >= 4);
        int m = n0 + n + k - 4;
        float d = 0.f;
        if (m >= 0 && m < N_) {
            float d0 = cs[0][n + k] - cs[0][n + 4];
            float d1 = cs[1][n + k] - cs[1][n + 4];
            float d2 = cs[2][n + k] - cs[2][n + 4];
            float dist = sqrtf(d0 * d0 + d1 * d1 + d2 * d2);
            d = fmaxf(1.f - dist * SIGMA_INV, 0.f);
        }
        dws[kk][n] = d;
    }
    __syncthreads();

    int ot = t >> 4, nt = t & 15;   // thread: o in [ot*4, ot*4+4), n in {nt + 16*j}
    float acc[4][8];
    #pragma unroll
    for (int a = 0; a < 4; ++a)
        #pragma unroll
        for (int j = 0; j < 8; ++j) acc[a][j] = 0.f;

    // base GEMM: center tap, dw == 1
    #pragma unroll
    for (int c4 = 0; c4 < 16; ++c4) {
        float4 wv[4], xv[8];
        #pragma unroll
        for (int a = 0; a < 4; ++a) wv[a] = *(float4*)&w4s[ot * 4 + a][c4 * 4];
        #pragma unroll
        for (int j = 0; j < 8; ++j) xv[j] = *(float4*)&xs[nt + 16 * j + 4][c4 * 4];
        #pragma unroll
        for (int a = 0; a < 4; ++a)
            #pragma unroll
            for (int j = 0; j < 8; ++j)
                acc[a][j] += wv[a].x * xv[j].x + wv[a].y * xv[j].y
                           + wv[a].z * xv[j].z + wv[a].w * xv[j].w;
    }
    // rare corrections: non-center taps with dw > 0
    #pragma unroll 1
    for (int j = 0; j < 8; ++j) {
        int n = nt + 16 * j;
        #pragma unroll 1
        for (int kk = 0; kk < 8; ++kk) {
            float d = dws[kk][n];
            if (d > 0.f) {
                int k = kk + (kk >= 4);
                const float* wg = cw + (size_t)(i * O_ + ot * 4) * C_ * K_ + k;
                #pragma unroll 1
                for (int c = 0; c < C_; ++c) {
                    float xv = d * xs[n + k][c];
                    #pragma unroll
                    for (int a = 0; a < 4; ++a)
                        acc[a][j] += xv * wg[((size_t)a * C_ + c) * K_];
                }
            }
        }
    }
    // write ybuf[i][b][p][o] (channel-contiguous for the fusion gather)
    float* yb = ybuf + ((size_t)i * B_ + b) * N_ * O_;
    #pragma unroll
    for (int j = 0; j < 8; ++j) {
        int p = n0 + nt + 16 * j;
        float4 v = make_float4(acc[0][j], acc[1][j], acc[2][j], acc[3][j]);
        *(float4*)&yb[(size_t)p * O_ + ot * 4] = v;
    }
}

// K5: fusion conv (1x1, 4O->O) with reindex gather folded in, plus BN partial stats.
__global__ __launch_bounds__(256) void k_fusion(
    const float* __restrict__ ybuf, const int* __restrict__ reidx,
    const float* __restrict__ fw, const float* __restrict__ fb,
    float* __restrict__ zbuf, float* __restrict__ stats)
{
    __shared__ float ys[NT][XSP];
    __shared__ float fws[O_][WP];
    int n0 = blockIdx.x * NT;
    int b  = blockIdx.y;
    int t  = threadIdx.x;
    int ot = t >> 4, nt = t & 15;
    float acc[4][8];
    #pragma unroll
    for (int a = 0; a < 4; ++a)
        #pragma unroll
        for (int j = 0; j < 8; ++j) acc[a][j] = 0.f;

    for (int i = 0; i < 4; ++i) {
        for (int idx = t; idx < NT * 16; idx += 256) {
            int row = idx >> 4, c4 = idx & 15;
            int pos = reidx[((size_t)b * N_ + n0 + row) * 4 + i];
            *(float4*)&ys[row][c4 * 4] =
                *(const float4*)&ybuf[(((size_t)i * B_ + b) * N_ + pos) * O_ + c4 * 4];
        }
        for (int idx = t; idx < O_ * 16; idx += 256) {
            int o = idx >> 4, c4 = idx & 15;
            *(float4*)&fws[o][c4 * 4] =
                *(const float4*)&fw[(size_t)o * (4 * O_) + i * O_ + c4 * 4];
        }
        __syncthreads();
        #pragma unroll
        for (int c4 = 0; c4 < 16; ++c4) {
            float4 wv[4], xv[8];
            #pragma unroll
            for (int a = 0; a < 4; ++a) wv[a] = *(float4*)&fws[ot * 4 + a][c4 * 4];
            #pragma unroll
            for (int j = 0; j < 8; ++j) xv[j] = *(float4*)&ys[nt + 16 * j][c4 * 4];
            #pragma unroll
            for (int a = 0; a < 4; ++a)
                #pragma unroll
                for (int j = 0; j < 8; ++j)
                    acc[a][j] += wv[a].x * xv[j].x + wv[a].y * xv[j].y
                               + wv[a].z * xv[j].z + wv[a].w * xv[j].w;
        }
        __syncthreads();
    }

    float sum_[4], sq_[4];
    #pragma unroll
    for (int a = 0; a < 4; ++a) {
        float bias = fb[ot * 4 + a];
        float s = 0.f, q = 0.f;
        #pragma unroll
        for (int j = 0; j < 8; ++j) {
            float z = acc[a][j] + bias;
            zbuf[((size_t)b * O_ + ot * 4 + a) * N_ + n0 + nt + 16 * j] = z;
            s += z; q += z * z;
        }
        sum_[a] = s; sq_[a] = q;
    }
    #pragma unroll
    for (int a = 0; a < 4; ++a) {
        float s = sum_[a], q = sq_[a];
        for (int m = 8; m >= 1; m >>= 1) {
            s += __shfl_xor(s, m, 16);
            q += __shfl_xor(q, m, 16);
        }
        if (nt == 0) {
            atomicAdd(&stats[ot * 4 + a], s);
            atomicAdd(&stats[O_ + ot * 4 + a], q);
        }
    }
}

// K6a: finalize BN stats -> scale/shift. Padded columns contribute bias only (2B per channel).
__global__ void k_bnstats(const float* __restrict__ st, const float* __restrict__ fb,
                          const float* __restrict__ gamma, const float* __restrict__ beta,
                          float* __restrict__ sc) {
    int o = threadIdx.x;
    float cnt = (float)(B_ * (N_ + 2));
    float bias = fb[o];
    float s = st[o] + 2.f * B_ * bias;
    float q = st[O_ + o] + 2.f * B_ * bias * bias;
    float mean = s / cnt;
    float var = q / cnt - mean * mean;
    float scale = gamma[o] / sqrtf(var + EPS);
    sc[o] = scale;
    sc[O_ + o] = beta[o] - mean * scale;
}

// K6b: apply BN + ReLU, emit padded layout [B][O][N+2]
__global__ void k_apply(const float* __restrict__ zbuf, const float* __restrict__ fb,
                        const float* __restrict__ sc, float* __restrict__ out) {
    int gid = blockIdx.x * 256 + threadIdx.x;
    const int total = B_ * O_ * (N_ + 2);
    if (gid >= total) return;
    int m = gid % (N_ + 2);
    int oc = gid / (N_ + 2);
    int o = oc % O_;
    int b = oc / O_;
    float v = (m == 0 || m == N_ + 1) ? fb[o] : zbuf[((size_t)b * O_ + o) * N_ + (m - 1)];
    float r = v * sc[o] + sc[O_ + o];
    out[gid] = fmaxf(r, 0.f);
}

extern "C" void kernel_launch(void* const* d_in, const int* in_sizes, int n_in,
                              void* d_out, int out_size, void* d_ws, size_t ws_size,
                              hipStream_t stream) {
    const float* input   = (const float*)d_in[0];
    const float* mc      = (const float*)d_in[1];
    const int*   indices = (const int*)d_in[2];
    const int*   reidx   = (const int*)d_in[3];
    const float* cw      = (const float*)d_in[4];
    const float* fw      = (const float*)d_in[5];
    const float* fb      = (const float*)d_in[6];
    const float* gamma   = (const float*)d_in[7];
    const float* beta    = (const float*)d_in[8];
    float* out = (float*)d_out;

    char* ws = (char*)d_ws;
    size_t off = 0;
    float* xt   = (float*)(ws + off); off += (size_t)B_ * N_ * C_ * 4;          // 16.8MB
    int*   cidx = (int*)  (ws + off); off += (size_t)4 * B_ * N_ * 4;           // 1MB
    float* ybuf = (float*)(ws + off); off += (size_t)4 * B_ * N_ * O_ * 4;      // 67.1MB
    float* zbuf = (float*)(ws + off); off += (size_t)B_ * O_ * N_ * 4;          // 16.8MB
    float* stats= (float*)(ws + off); off += 256 * 4;

    hipMemsetAsync(stats, 0, 256 * sizeof(float), stream);
    k_transpose<<<dim3(N_ / 64, B_), 256, 0, stream>>>(input, xt);
    for (int s = 0; s < 4; ++s)
        k_compose<<<(B_ * N_) / 256, 256, 0, stream>>>(indices, cidx, s);
    k_conv<<<dim3(N_ / NT, B_, 4), 256, 0, stream>>>(xt, cidx, mc, cw, ybuf);
    k_fusion<<<dim3(N_ / NT, B_), 256, 0, stream>>>(ybuf, reidx, fw, fb, zbuf, stats);
    k_bnstats<<<1, 64, 0, stream>>>(stats, fb, gamma, beta, stats + 128);
    k_apply<<<(B_ * O_ * (N_ + 2) + 255) / 256, 256, 0, stream>>>(zbuf, fb, stats + 128, out);
}

// Round 2
// 300.887 us; speedup vs baseline: 1.3124x; 1.3124x over previous
//
#include <hip/hip_runtime.h>

#define K_ 9
#define SIGMA_INV 12.5f
#define EPS 1e-5f
#define B_ 4
#define C_ 64
#define O_ 64
#define N_ 16384
#define CAP 32768

// K1: transpose input [B][C][N] -> xt [B][N][C]
__global__ __launch_bounds__(256) void k_transpose(const float* __restrict__ in,
                                                   float* __restrict__ xt) {
    __shared__ float tile[64][65];
    int b = blockIdx.y;
    int n0 = blockIdx.x * 64;
    int t = threadIdx.x;
    for (int rep = 0; rep < 16; ++rep) {
        int idx = rep * 256 + t;
        int c = idx >> 6, j = idx & 63;
        tile[c][j] = in[((size_t)b * C_ + c) * N_ + n0 + j];
    }
    __syncthreads();
    for (int rep = 0; rep < 16; ++rep) {
        int idx = rep * 256 + t;
        int j = idx >> 6, c = idx & 63;
        xt[((size_t)b * N_ + n0 + j) * C_ + c] = tile[c][j];
    }
}

// K2: compose gather chains. cidx[i][b][n]
__global__ void k_compose(const int* __restrict__ indices, int* __restrict__ cidx, int step) {
    int gid = blockIdx.x * blockDim.x + threadIdx.x;  // over B*N
    int b = gid / N_, n = gid - b * N_;
    int id = indices[((size_t)b * N_ + n) * 4 + step];
    int v;
    if (step == 0) v = id;
    else v = cidx[(size_t)(step - 1) * B_ * N_ + (size_t)b * N_ + id];
    cidx[(size_t)step * B_ * N_ + (size_t)b * N_ + n] = v;
}

// K3: h[i][b][n] = cidx[i][b][reidx[b][n][i]]
__global__ void k_hmap(const int* __restrict__ reidx, const int* __restrict__ cidx,
                       int* __restrict__ h) {
    int gid = blockIdx.x * 256 + threadIdx.x;
    int b = gid / N_, n = gid - b * N_;
    #pragma unroll
    for (int i = 0; i < 4; ++i) {
        int p = reidx[((size_t)b * N_ + n) * 4 + i];
        h[(size_t)(i * 4 + b) * N_ + n] = cidx[(size_t)(i * 4 + b) * N_ + p];
    }
}

// K4: prep: M_i = FW_i * W4_i ; Wt[i][k][c][o] ; FWt[i*64+c][o]
__global__ __launch_bounds__(256) void k_prep(const float* __restrict__ cw,
                                              const float* __restrict__ fw,
                                              float* __restrict__ Ms,
                                              float* __restrict__ Wt,
                                              float* __restrict__ FWt) {
    int bid = blockIdx.x, t = threadIdx.x;
    if (bid < 4) {
        __shared__ float w4[64][65];
        __shared__ float fws[64][65];
        int i = bid;
        for (int idx = t; idx < 4096; idx += 256) {
            int op = idx >> 6, c = idx & 63;
            w4[op][c]  = cw[(((size_t)(i * 64 + op)) * 64 + c) * 9 + 4];
            fws[op][c] = fw[(size_t)op * 256 + i * 64 + c];
        }
        __syncthreads();
        int o = t >> 2, cb = (t & 3) * 16;
        float acc[16];
        #pragma unroll
        for (int j = 0; j < 16; ++j) acc[j] = 0.f;
        for (int op = 0; op < 64; ++op) {
            float f = fws[o][op];
            #pragma unroll
            for (int j = 0; j < 16; ++j) acc[j] += f * w4[op][cb + j];
        }
        #pragma unroll
        for (int j = 0; j < 16; ++j) Ms[(size_t)i * 4096 + o * 64 + cb + j] = acc[j];
    } else if (bid < 40) {
        int idx2 = bid - 4;
        int i = idx2 / 9, k = idx2 - i * 9;
        for (int idx = t; idx < 4096; idx += 256) {
            int c = idx >> 6, o = idx & 63;
            Wt[(size_t)(i * 9 + k) * 4096 + c * 64 + o] =
                cw[(((size_t)(i * 64 + o)) * 64 + c) * 9 + k];
        }
    } else {
        int i = bid - 40;
        for (int idx = t; idx < 4096; idx += 256) {
            int c = idx >> 6, o = idx & 63;
            FWt[(size_t)(i * 64 + c) * 64 + o] = fw[(size_t)o * 256 + i * 64 + c];
        }
    }
}

// K5: scan all (i,b,p) for non-center taps with dw>0; append compact entries.
__global__ __launch_bounds__(256) void k_scan(const float* __restrict__ mc,
                                              int* __restrict__ flag,
                                              int* __restrict__ emeta,
                                              float* __restrict__ ed,
                                              int* __restrict__ cnt) {
    __shared__ float cs[3][264];
    int n0 = blockIdx.x * 256, b = blockIdx.y, i = blockIdx.z, t = threadIdx.x;
    for (int idx = t; idx < 3 * 264; idx += 256) {
        int a = idx / 264, r = idx - a * 264;
        int m = n0 + r - 4;
        cs[a][r] = (m >= 0 && m < N_) ? mc[(((size_t)b * 3 + a) * N_ + m) * 4 + i] : 1e9f;
    }
    __syncthreads();
    int p = n0 + t;
    float c0 = cs[0][t + 4], c1 = cs[1][t + 4], c2 = cs[2][t + 4];
    float d[8];
    bool any = false;
    #pragma unroll
    for (int kk = 0; kk < 8; ++kk) {
        int k = kk + (kk >= 4);
        float d0 = cs[0][t + k] - c0, d1 = cs[1][t + k] - c1, d2 = cs[2][t + k] - c2;
        float dist = sqrtf(d0 * d0 + d1 * d1 + d2 * d2);
        float dd = 1.f - dist * SIGMA_INV;
        d[kk] = dd > 0.f ? dd : 0.f;
        any = any || (dd > 0.f);
    }
    if (any) {
        int e = atomicAdd(cnt, 1);
        if (e < CAP) {
            emeta[e] = ((i * 4 + b) << 14) | p;
            #pragma unroll
            for (int kk = 0; kk < 8; ++kk) ed[(size_t)e * 8 + kk] = d[kk];
            flag[(size_t)(i * 4 + b) * N_ + p] = e + 1;
        }
    }
}

// K6: per correction entry: vz = FW_i * (sum_k d_k * W_ik * x_window) -> zcorr[e][64]
__global__ __launch_bounds__(64) void k_corr(const float* __restrict__ xt,
                                             const int* __restrict__ cidx,
                                             const float* __restrict__ Wt,
                                             const float* __restrict__ FWt,
                                             const int* __restrict__ emeta,
                                             const float* __restrict__ ed,
                                             const int* __restrict__ cnt,
                                             float* __restrict__ zcorr) {
    __shared__ float xls[64];
    __shared__ float ycs[64];
    int t = threadIdx.x;
    int n = *cnt;
    if (n > CAP) n = CAP;
    for (int e = blockIdx.x; e < n; e += gridDim.x) {
        int meta = emeta[e];
        int ib = meta >> 14, p = meta & 16383;
        int i = ib >> 2, b = ib & 3;
        const int* ci = cidx + (size_t)ib * N_;
        float yc = 0.f;
        for (int kk = 0; kk < 8; ++kk) {
            float dd = ed[(size_t)e * 8 + kk];   // wave-uniform
            if (dd <= 0.f) continue;
            int k = kk + (kk >= 4);
            int row = ci[p + k - 4];
            xls[t] = xt[((size_t)b * N_ + row) * 64 + t];
            __syncthreads();
            const float* wt = Wt + (size_t)(i * 9 + k) * 4096;
            float s = 0.f;
            #pragma unroll 4
            for (int c = 0; c < 64; ++c) s += wt[c * 64 + t] * xls[c];
            yc += dd * s;
            __syncthreads();
        }
        ycs[t] = yc;
        __syncthreads();
        const float* fwt = FWt + (size_t)i * 4096;
        float v = 0.f;
        #pragma unroll 4
        for (int c = 0; c < 64; ++c) v += fwt[c * 64 + t] * ycs[c];
        zcorr[(size_t)e * 64 + t] = v;
        __syncthreads();
    }
}

// K7: fused z = sum_i M_i * x[:,h_i(n)] (+corrections) + bias, BN partial stats.
__global__ __launch_bounds__(256) void k_fused(const float* __restrict__ xt,
                                               const int* __restrict__ h,
                                               const int* __restrict__ flag,
                                               const int* __restrict__ reidx,
                                               const float* __restrict__ Ms,
                                               const float* __restrict__ zcorr,
                                               const float* __restrict__ fb,
                                               float* __restrict__ zbuf,
                                               float* __restrict__ stats) {
    __shared__ float xg[64][68];
    __shared__ float ms[64][68];
    __shared__ int hs[4][64];
    __shared__ int fs[4][64];
    int bid = blockIdx.x;
    int b = (bid & 7) >> 1;                       // XCD-pair per batch (L2 locality)
    int nb = ((bid >> 3) << 1) | (bid & 1);
    int n0 = nb * 64;
    int t = threadIdx.x;
    {   // stage composed indices + correction flags for this block's 64 positions
        int i = t >> 6, nl = t & 63;
        int n = n0 + nl;
        int p = reidx[((size_t)b * N_ + n) * 4 + i];
        fs[i][nl] = flag[(size_t)(i * 4 + b) * N_ + p];
        hs[i][nl] = h[(size_t)(i * 4 + b) * N_ + n];
    }
    int ot = t >> 4, nt = t & 15;
    float acc[4][4];
    #pragma unroll
    for (int a = 0; a < 4; ++a)
        #pragma unroll
        for (int j = 0; j < 4; ++j) acc[a][j] = 0.f;

    for (int i = 0; i < 4; ++i) {
        __syncthreads();
        #pragma unroll
        for (int r = 0; r < 4; ++r) {
            int idx = r * 256 + t;
            int row = idx >> 4, c4 = idx & 15;
            int pos = hs[i][row];
            *(float4*)&xg[row][c4 * 4] =
                *(const float4*)&xt[((size_t)b * N_ + pos) * 64 + c4 * 4];
        }
        #pragma unroll
        for (int r = 0; r < 4; ++r) {
            int idx = r * 256 + t;
            int row = idx >> 4, c4 = idx & 15;
            *(float4*)&ms[row][c4 * 4] =
                *(const float4*)&Ms[(size_t)i * 4096 + row * 64 + c4 * 4];
        }
        __syncthreads();
        #pragma unroll
        for (int c4 = 0; c4 < 16; ++c4) {
            float4 mv[4], xv[4];
            #pragma unroll
            for (int a = 0; a < 4; ++a) mv[a] = *(float4*)&ms[ot * 4 + a][c4 * 4];
            #pragma unroll
            for (int j = 0; j < 4; ++j) xv[j] = *(float4*)&xg[nt + 16 * j][c4 * 4];
            #pragma unroll
            for (int a = 0; a < 4; ++a)
                #pragma unroll
                for (int j = 0; j < 4; ++j)
                    acc[a][j] += mv[a].x * xv[j].x + mv[a].y * xv[j].y
                               + mv[a].z * xv[j].z + mv[a].w * xv[j].w;
        }
    }
    // rare corrections
    #pragma unroll
    for (int j = 0; j < 4; ++j) {
        int nl = nt + 16 * j;
        #pragma unroll
        for (int i = 0; i < 4; ++i) {
            int f = fs[i][nl];
            if (f > 0) {
                const float4 vc = *(const float4*)&zcorr[(size_t)(f - 1) * 64 + ot * 4];
                acc[0][j] += vc.x; acc[1][j] += vc.y; acc[2][j] += vc.z; acc[3][j] += vc.w;
            }
        }
    }
    // bias + store + BN partial stats
    float sum_[4], sq_[4];
    #pragma unroll
    for (int a = 0; a < 4; ++a) {
        float bias = fb[ot * 4 + a];
        float s = 0.f, q = 0.f;
        #pragma unroll
        for (int j = 0; j < 4; ++j) {
            float z = acc[a][j] + bias;
            zbuf[((size_t)b * O_ + ot * 4 + a) * N_ + n0 + nt + 16 * j] = z;
            s += z; q += z * z;
        }
        sum_[a] = s; sq_[a] = q;
    }
    #pragma unroll
    for (int a = 0; a < 4; ++a) {
        float s = sum_[a], q = sq_[a];
        for (int m = 8; m >= 1; m >>= 1) {
            s += __shfl_xor(s, m, 16);
            q += __shfl_xor(q, m, 16);
        }
        if (nt == 0) {
            atomicAdd(&stats[ot * 4 + a], s);
            atomicAdd(&stats[O_ + ot * 4 + a], q);
        }
    }
}

// K8: finalize BN stats (padded cols see bias only: 2B per channel)
__global__ void k_bnstats(const float* __restrict__ st, const float* __restrict__ fb,
                          const float* __restrict__ gamma, const float* __restrict__ beta,
                          float* __restrict__ sc) {
    int o = threadIdx.x;
    float cnt = (float)(B_ * (N_ + 2));
    float bias = fb[o];
    float s = st[o] + 2.f * B_ * bias;
    float q = st[O_ + o] + 2.f * B_ * bias * bias;
    float mean = s / cnt;
    float var = q / cnt - mean * mean;
    float scale = gamma[o] / sqrtf(var + EPS);
    sc[o] = scale;
    sc[O_ + o] = beta[o] - mean * scale;
}

// K9: BN + ReLU, emit padded layout [B][O][N+2]
__global__ void k_apply(const float* __restrict__ zbuf, const float* __restrict__ fb,
                        const float* __restrict__ sc, float* __restrict__ out) {
    int gid = blockIdx.x * 256 + threadIdx.x;
    const int total = B_ * O_ * (N_ + 2);
    if (gid >= total) return;
    int m = gid % (N_ + 2);
    int oc = gid / (N_ + 2);
    int o = oc % O_;
    int b = oc / O_;
    float v = (m == 0 || m == N_ + 1) ? fb[o] : zbuf[((size_t)b * O_ + o) * N_ + (m - 1)];
    float r = v * sc[o] + sc[O_ + o];
    out[gid] = fmaxf(r, 0.f);
}

extern "C" void kernel_launch(void* const* d_in, const int* in_sizes, int n_in,
                              void* d_out, int out_size, void* d_ws, size_t ws_size,
                              hipStream_t stream) {
    const float* input   = (const float*)d_in[0];
    const float* mc      = (const float*)d_in[1];
    const int*   indices = (const int*)d_in[2];
    const int*   reidx   = (const int*)d_in[3];
    const float* cw      = (const float*)d_in[4];
    const float* fw      = (const float*)d_in[5];
    const float* fb      = (const float*)d_in[6];
    const float* gamma   = (const float*)d_in[7];
    const float* beta    = (const float*)d_in[8];
    float* out = (float*)d_out;

    char* ws = (char*)d_ws;
    size_t off = 0;
    float* xt    = (float*)(ws + off); off += (size_t)B_ * N_ * C_ * 4;     // 16.8MB
    int*   cidx  = (int*)  (ws + off); off += (size_t)4 * B_ * N_ * 4;      // 1MB
    int*   h     = (int*)  (ws + off); off += (size_t)4 * B_ * N_ * 4;      // 1MB
    int*   flag  = (int*)  (ws + off); off += (size_t)4 * B_ * N_ * 4;      // 1MB
    float* Ms    = (float*)(ws + off); off += (size_t)4 * 64 * 64 * 4;
    float* Wt    = (float*)(ws + off); off += (size_t)4 * 9 * 64 * 64 * 4;
    float* FWt   = (float*)(ws + off); off += (size_t)256 * 64 * 4;
    int*   emeta = (int*)  (ws + off); off += (size_t)CAP * 4;
    float* ed    = (float*)(ws + off); off += (size_t)CAP * 8 * 4;
    float* zcorr = (float*)(ws + off); off += (size_t)CAP * 64 * 4;         // 8MB
    float* zbuf  = (float*)(ws + off); off += (size_t)B_ * O_ * N_ * 4;     // 16.8MB
    float* stats = (float*)(ws + off); off += 256 * 4;
    int*   cnt   = (int*)  (ws + off); off += 64;

    hipMemsetAsync(stats, 0, 256 * sizeof(float), stream);
    hipMemsetAsync(cnt, 0, sizeof(int), stream);
    hipMemsetAsync(flag, 0, (size_t)4 * B_ * N_ * 4, stream);

    k_transpose<<<dim3(N_ / 64, B_), 256, 0, stream>>>(input, xt);
    for (int s = 0; s < 4; ++s)
        k_compose<<<(B_ * N_) / 256, 256, 0, stream>>>(indices, cidx, s);
    k_prep<<<44, 256, 0, stream>>>(cw, fw, Ms, Wt, FWt);
    k_scan<<<dim3(N_ / 256, B_, 4), 256, 0, stream>>>(mc, flag, emeta, ed, cnt);
    k_hmap<<<(B_ * N_) / 256, 256, 0, stream>>>(reidx, cidx, h);
    k_corr<<<256, 64, 0, stream>>>(xt, cidx, Wt, FWt, emeta, ed, cnt, zcorr);
    k_fused<<<1024, 256, 0, stream>>>(xt, h, flag, reidx, Ms, zcorr, fb, zbuf, stats);
    k_bnstats<<<1, 64, 0, stream>>>(stats, fb, gamma, beta, stats + 128);
    k_apply<<<(B_ * O_ * (N_ + 2) + 255) / 256, 256, 0, stream>>>(zbuf, fb, stats + 128, out);
}

// Round 3
// 171.142 us; speedup vs baseline: 2.3073x; 1.7581x over previous
//
#include <hip/hip_runtime.h>

#define K_ 9
#define SIGMA_INV 12.5f
#define EPS 1e-5f
#define B_ 4
#define C_ 64
#define O_ 64
#define N_ 16384
#define CAP 32768

typedef __attribute__((ext_vector_type(8))) short short8;
typedef __attribute__((ext_vector_type(4))) float f32x4;

__device__ __forceinline__ unsigned short f2bf(float f) {
    union { float f; unsigned u; } v; v.f = f;
    unsigned r = v.u + 0x7fffu + ((v.u >> 16) & 1u);   // round-nearest-even
    return (unsigned short)(r >> 16);
}
__device__ __forceinline__ float bf2f(unsigned short h) {
    union { unsigned u; float f; } v; v.u = ((unsigned)h) << 16;
    return v.f;
}
__device__ __forceinline__ void gload16(const void* g, void* l) {
    __builtin_amdgcn_global_load_lds((const __attribute__((address_space(1))) unsigned int*)g,
                                     (__attribute__((address_space(3))) unsigned int*)l,
                                     16, 0, 0);
}

// ---------------------------------------------------------------------------
// K_setup: heterogeneous roles.
//  [0,1024)      : transpose+bf16-convert tile (64n x 64c)
//  [1024,1280)   : scan (all 4 i at once via float4 mc reads)
//  [1280,1324)   : prep (4x M->Mfrag, 36x Wt, 4x FWt)
//  [1324,1580)   : compose step 0
// ---------------------------------------------------------------------------
__global__ __launch_bounds__(256) void k_setup(
    const float* __restrict__ in, const float* __restrict__ mc,
    const int* __restrict__ indices,
    const float* __restrict__ cw, const float* __restrict__ fw,
    unsigned short* __restrict__ xtb, int* __restrict__ cidx,
    unsigned short* __restrict__ Mfrag, float* __restrict__ Wt,
    float* __restrict__ FWt,
    int* __restrict__ flag, int* __restrict__ emeta,
    float* __restrict__ ed, int* __restrict__ cnt)
{
    int bid = blockIdx.x, t = threadIdx.x;
    if (bid < 1024) {                                    // ---- transpose + cvt
        __shared__ float tile[64][65];
        int b = bid & 3, n0 = (bid >> 2) * 64;
        for (int rep = 0; rep < 16; ++rep) {
            int idx = rep * 256 + t;
            int c = idx >> 6, j = idx & 63;
            tile[c][j] = in[((size_t)b * C_ + c) * N_ + n0 + j];
        }
        __syncthreads();
        for (int rep = 0; rep < 4; ++rep) {              // ushort4 packed writes
            int idx = rep * 256 + t;
            int j = idx >> 4, c4 = (idx & 15) * 4;
            ushort4 o;
            o.x = f2bf(tile[c4 + 0][j]); o.y = f2bf(tile[c4 + 1][j]);
            o.z = f2bf(tile[c4 + 2][j]); o.w = f2bf(tile[c4 + 3][j]);
            *(ushort4*)&xtb[((size_t)b * N_ + n0 + j) * 64 + c4] = o;
        }
    } else if (bid < 1280) {                             // ---- scan (4 i at once)
        __shared__ float cs[3][264][4];
        int sb = bid - 1024;
        int b = sb & 3, n0 = (sb >> 2) * 256;
        for (int idx = t; idx < 3 * 264; idx += 256) {
            int a = idx / 264, r = idx - a * 264;
            int m = n0 + r - 4;
            f32x4 v;
            if (m >= 0 && m < N_) v = *(const f32x4*)&mc[(((size_t)b * 3 + a) * N_ + m) * 4];
            else { v[0] = 1e9f; v[1] = 1e9f; v[2] = 1e9f; v[3] = 1e9f; }
            *(f32x4*)&cs[a][r][0] = v;
        }
        __syncthreads();
        int p = n0 + t;
        for (int i = 0; i < 4; ++i) {
            float c0 = cs[0][t + 4][i], c1 = cs[1][t + 4][i], c2 = cs[2][t + 4][i];
            float d[8]; bool any = false;
            #pragma unroll
            for (int kk = 0; kk < 8; ++kk) {
                int k = kk + (kk >= 4);
                float d0 = cs[0][t + k][i] - c0, d1 = cs[1][t + k][i] - c1,
                      d2 = cs[2][t + k][i] - c2;
                float dist = sqrtf(d0 * d0 + d1 * d1 + d2 * d2);
                float dd = 1.f - dist * SIGMA_INV;
                d[kk] = dd > 0.f ? dd : 0.f;
                any = any || (dd > 0.f);
            }
            if (any) {
                int e = atomicAdd(cnt, 1);
                if (e < CAP) {
                    emeta[e] = ((i * 4 + b) << 14) | p;
                    #pragma unroll
                    for (int kk = 0; kk < 8; ++kk) ed[(size_t)e * 8 + kk] = d[kk];
                    flag[(size_t)(i * 4 + b) * N_ + p] = e + 1;
                }
            }
        }
    } else if (bid < 1324) {                             // ---- prep
        int pb = bid - 1280;
        if (pb < 4) {
            __shared__ float w4[64][65];
            __shared__ float fws[64][65];
            int i = pb;
            for (int idx = t; idx < 4096; idx += 256) {
                int op = idx >> 6, c = idx & 63;
                w4[op][c]  = cw[(((size_t)(i * 64 + op)) * 64 + c) * 9 + 4];
                fws[op][c] = fw[(size_t)op * 256 + i * 64 + c];
            }
            __syncthreads();
            int o = t >> 2, cb = (t & 3) * 16;
            float acc[16];
            #pragma unroll
            for (int j = 0; j < 16; ++j) acc[j] = 0.f;
            for (int op = 0; op < 64; ++op) {
                float f = fws[o][op];
                #pragma unroll
                for (int j = 0; j < 16; ++j) acc[j] += f * w4[op][cb + j];
            }
            // emit MFMA A-fragment layout: Mfrag[w][s][lane][8]
            // value M_i[o][c] -> s=i*2+(c>>5), lane=(((c>>3)&3)<<4)|(o&15), j=c&7, w=o>>4
            #pragma unroll
            for (int j = 0; j < 16; ++j) {
                int c = cb + j;
                int s = i * 2 + (c >> 5);
                int l = (((c >> 3) & 3) << 4) | (o & 15);
                int w_ = o >> 4;
                Mfrag[(((size_t)w_ * 8 + s) * 64 + l) * 8 + (c & 7)] = f2bf(acc[j]);
            }
        } else if (pb < 40) {
            int idx2 = pb - 4;
            int i = idx2 / 9, k = idx2 - i * 9;
            for (int idx = t; idx < 4096; idx += 256) {
                int c = idx >> 6, o = idx & 63;
                Wt[(size_t)(i * 9 + k) * 4096 + c * 64 + o] =
                    cw[(((size_t)(i * 64 + o)) * 64 + c) * 9 + k];
            }
        } else {
            int i = pb - 40;
            for (int idx = t; idx < 4096; idx += 256) {
                int c = idx >> 6, o = idx & 63;
                FWt[(size_t)(i * 64 + c) * 64 + o] = fw[(size_t)o * 256 + i * 64 + c];
            }
        }
    } else {                                             // ---- compose step 0
        int gid = (bid - 1324) * 256 + t;                // over B*N
        int b = gid >> 14, n = gid & (N_ - 1);
        cidx[(size_t)b * N_ + n] = indices[((size_t)b * N_ + n) * 4];
    }
}

// compose steps 1..3
__global__ void k_compose(const int* __restrict__ indices, int* __restrict__ cidx, int step) {
    int gid = blockIdx.x * blockDim.x + threadIdx.x;
    int b = gid >> 14, n = gid & (N_ - 1);
    int id = indices[((size_t)b * N_ + n) * 4 + step];
    cidx[(size_t)step * B_ * N_ + (size_t)b * N_ + n] =
        cidx[(size_t)(step - 1) * B_ * N_ + (size_t)b * N_ + id];
}

// h[i][b][n] = cidx[i][b][reidx[b][n][i]]
__global__ void k_hmap(const int* __restrict__ reidx, const int* __restrict__ cidx,
                       int* __restrict__ h) {
    int gid = blockIdx.x * 256 + threadIdx.x;
    int b = gid >> 14, n = gid & (N_ - 1);
    #pragma unroll
    for (int i = 0; i < 4; ++i) {
        int p = reidx[((size_t)b * N_ + n) * 4 + i];
        h[(size_t)(i * 4 + b) * N_ + n] = cidx[(size_t)(i * 4 + b) * N_ + p];
    }
}

// corrections: one wave per entry (grid-stride). zcorr[e][64] fp32.
__global__ __launch_bounds__(64) void k_corr(
    const unsigned short* __restrict__ xtb, const int* __restrict__ cidx,
    const float* __restrict__ Wt, const float* __restrict__ FWt,
    const int* __restrict__ emeta, const float* __restrict__ ed,
    const int* __restrict__ cnt, float* __restrict__ zcorr)
{
    __shared__ float xls[8][64];
    __shared__ float ycs[64];
    int t = threadIdx.x;
    int n = *cnt; if (n > CAP) n = CAP;
    for (int e = blockIdx.x; e < n; e += gridDim.x) {
        int meta = emeta[e];
        int ib = meta >> 14, p = meta & 16383;
        int i = ib >> 2, b = ib & 3;
        const int* ci = cidx + (size_t)ib * N_;
        float dd[8];
        #pragma unroll
        for (int kk = 0; kk < 8; ++kk) dd[kk] = ed[(size_t)e * 8 + kk];
        // prefetch all active rows concurrently
        #pragma unroll
        for (int kk = 0; kk < 8; ++kk) {
            if (dd[kk] > 0.f) {
                int k = kk + (kk >= 4);
                int row = ci[p + k - 4];
                xls[kk][t] = bf2f(xtb[((size_t)b * N_ + row) * 64 + t]);
            }
        }
        __syncthreads();
        float y = 0.f;
        #pragma unroll 1
        for (int kk = 0; kk < 8; ++kk) {
            if (dd[kk] > 0.f) {
                int k = kk + (kk >= 4);
                const float* w = Wt + (size_t)(i * 9 + k) * 4096;
                float s0 = 0.f, s1 = 0.f, s2 = 0.f, s3 = 0.f;
                #pragma unroll
                for (int c = 0; c < 64; c += 4) {
                    s0 += w[(c + 0) * 64 + t] * xls[kk][c + 0];
                    s1 += w[(c + 1) * 64 + t] * xls[kk][c + 1];
                    s2 += w[(c + 2) * 64 + t] * xls[kk][c + 2];
                    s3 += w[(c + 3) * 64 + t] * xls[kk][c + 3];
                }
                y += dd[kk] * (((s0 + s1) + (s2 + s3)));
            }
        }
        ycs[t] = y;
        __syncthreads();
        const float* fwt = FWt + (size_t)i * 4096;
        float v0 = 0.f, v1 = 0.f, v2 = 0.f, v3 = 0.f;
        #pragma unroll
        for (int c = 0; c < 64; c += 4) {
            v0 += fwt[(c + 0) * 64 + t] * ycs[c + 0];
            v1 += fwt[(c + 1) * 64 + t] * ycs[c + 1];
            v2 += fwt[(c + 2) * 64 + t] * ycs[c + 2];
            v3 += fwt[(c + 3) * 64 + t] * ycs[c + 3];
        }
        zcorr[(size_t)e * 64 + t] = (v0 + v1) + (v2 + v3);
        __syncthreads();
    }
}

// ---------------------------------------------------------------------------
// k_fused: Z[64o x 64pos] = concat_i(M_i) [64x256] . stack_i(xg_i) [256x64]
// via mfma_f32_16x16x32_bf16. Gathers staged via global_load_lds with
// source-chunk XOR swizzle (key = row&7) so B-frag ds_read_b128 is conflict-free.
// ---------------------------------------------------------------------------
__global__ __launch_bounds__(256) void k_fused(
    const unsigned short* __restrict__ xtb, const int* __restrict__ h,
    const int* __restrict__ flag, const int* __restrict__ reidx,
    const unsigned short* __restrict__ Mfrag, const float* __restrict__ zcorr,
    const float* __restrict__ fb, float* __restrict__ zbuf,
    float* __restrict__ stats)
{
    __shared__ __align__(16) unsigned short xg[256 * 64];   // [i*64+pos][c] bf16, chunk-swizzled
    __shared__ int hs[256];
    __shared__ int fs[256];
    int bid = blockIdx.x;
    int b = (bid & 7) >> 1;                        // batch -> XCD pair (L2 locality)
    int nb = ((bid >> 3) << 1) | (bid & 1);
    int n0 = nb * 64;
    int t = threadIdx.x;
    int lane = t & 63, w = t >> 6;

    {   // stage composed-gather indices + correction flags
        int i = t >> 6, p = t & 63;
        hs[t] = h[(size_t)(i * 4 + b) * N_ + n0 + p];
        int pr = reidx[((size_t)b * N_ + n0 + p) * 4 + i];
        fs[t] = flag[(size_t)(i * 4 + b) * N_ + pr];
    }
    // A-fragments: wave w owns o-rows [w*16, w*16+16), K=256 in 8 steps
    short8 af[8];
    #pragma unroll
    for (int s = 0; s < 8; ++s)
        af[s] = *(const short8*)&Mfrag[(((size_t)w * 8 + s) * 64 + lane) * 8];
    __syncthreads();

    // gather-stage: wave w stages ordering i=w (64 rows x 128B), 8 issues deep
    int hvv[8];
    #pragma unroll
    for (int it = 0; it < 8; ++it)
        hvv[it] = hs[w * 64 + it * 8 + (lane >> 3)];
    #pragma unroll
    for (int it = 0; it < 8; ++it) {
        int p = it * 8 + (lane >> 3);
        int cg = (lane & 7) ^ (p & 7);             // source-chunk swizzle
        const unsigned short* gp = xtb + ((size_t)b * N_ + hvv[it]) * 64 + cg * 8;
        gload16(gp, &xg[(size_t)(w * 64 + it * 8) * 64]);
    }
    asm volatile("s_waitcnt vmcnt(0)" ::: "memory");
    __syncthreads();

    // MFMA: 4 col-tiles x 8 K-steps
    f32x4 acc[4];
    #pragma unroll
    for (int ct = 0; ct < 4; ++ct) { acc[ct][0]=0.f; acc[ct][1]=0.f; acc[ct][2]=0.f; acc[ct][3]=0.f; }
    #pragma unroll
    for (int s = 0; s < 8; ++s) {
        int i2 = s >> 1;
        int cg = (s & 1) * 4 + (lane >> 4);
        #pragma unroll
        for (int ct = 0; ct < 4; ++ct) {
            int pos = ct * 16 + (lane & 15);
            const short8 bf = *(const short8*)((const char*)xg +
                ((size_t)(i2 * 64 + pos) * 128) + ((cg ^ (pos & 7)) * 16));
            acc[ct] = __builtin_amdgcn_mfma_f32_16x16x32_bf16(af[s], bf, acc[ct], 0, 0, 0);
        }
    }

    // epilogue: corrections + bias + store + BN partial stats
    int og = w * 16 + (lane >> 4) * 4;             // lane's 4 output rows
    const f32x4 bias4 = *(const f32x4*)&fb[og];
    float sums[4] = {0.f, 0.f, 0.f, 0.f}, sqs[4] = {0.f, 0.f, 0.f, 0.f};
    #pragma unroll
    for (int ct = 0; ct < 4; ++ct) {
        int p = ct * 16 + (lane & 15);
        #pragma unroll
        for (int i = 0; i < 4; ++i) {
            int f = fs[i * 64 + p];
            if (f > 0) {
                const f32x4 vc = *(const f32x4*)&zcorr[(size_t)(f - 1) * 64 + og];
                acc[ct] += vc;
            }
        }
        f32x4 z = acc[ct] + bias4;
        int n = n0 + p;
        #pragma unroll
        for (int r = 0; r < 4; ++r) {
            zbuf[((size_t)b * O_ + og + r) * N_ + n] = z[r];
            sums[r] += z[r]; sqs[r] += z[r] * z[r];
        }
    }
    #pragma unroll
    for (int r = 0; r < 4; ++r) {
        float s = sums[r], q = sqs[r];
        for (int m = 8; m >= 1; m >>= 1) {
            s += __shfl_xor(s, m);
            q += __shfl_xor(q, m);
        }
        if ((lane & 15) == 0) {
            atomicAdd(&stats[og + r], s);
            atomicAdd(&stats[O_ + og + r], q);
        }
    }
}

__global__ void k_bnstats(const float* __restrict__ st, const float* __restrict__ fb,
                          const float* __restrict__ gamma, const float* __restrict__ beta,
                          float* __restrict__ sc) {
    int o = threadIdx.x;
    float cnt = (float)(B_ * (N_ + 2));
    float bias = fb[o];
    float s = st[o] + 2.f * B_ * bias;
    float q = st[O_ + o] + 2.f * B_ * bias * bias;
    float mean = s / cnt;
    float var = q / cnt - mean * mean;
    float scale = gamma[o] / sqrtf(var + EPS);
    sc[o] = scale;
    sc[O_ + o] = beta[o] - mean * scale;
}

// BN + ReLU -> out [B][O][N+2]; blocks [0,4096) interior (float4), block 4096 pads
__global__ __launch_bounds__(256) void k_apply(const float* __restrict__ zbuf,
                                               const float* __restrict__ fb,
                                               const float* __restrict__ sc,
                                               float* __restrict__ out) {
    int bid = blockIdx.x, t = threadIdx.x;
    if (bid < 4096) {
        int gid = bid * 256 + t;
        int row = gid >> 12;                       // (b*64+o), 4096 float4 per row
        int n = (gid & 4095) * 4;
        int o = row & 63;
        float scale = sc[o], shift = sc[O_ + o];
        f32x4 z = *(const f32x4*)&zbuf[(size_t)row * N_ + n];
        size_t ob = (size_t)row * (N_ + 2) + 1 + n;
        #pragma unroll
        for (int r = 0; r < 4; ++r)
            out[ob + r] = fmaxf(z[r] * scale + shift, 0.f);
    } else {
        int row = t;                               // 256 rows
        int o = row & 63;
        float v = fmaxf(fb[o] * sc[o] + sc[O_ + o], 0.f);
        out[(size_t)row * (N_ + 2)] = v;
        out[(size_t)row * (N_ + 2) + N_ + 1] = v;
    }
}

extern "C" void kernel_launch(void* const* d_in, const int* in_sizes, int n_in,
                              void* d_out, int out_size, void* d_ws, size_t ws_size,
                              hipStream_t stream) {
    const float* input   = (const float*)d_in[0];
    const float* mc      = (const float*)d_in[1];
    const int*   indices = (const int*)d_in[2];
    const int*   reidx   = (const int*)d_in[3];
    const float* cw      = (const float*)d_in[4];
    const float* fw      = (const float*)d_in[5];
    const float* fb      = (const float*)d_in[6];
    const float* gamma   = (const float*)d_in[7];
    const float* beta    = (const float*)d_in[8];
    float* out = (float*)d_out;

    char* ws = (char*)d_ws;
    size_t off = 0;
    auto alloc = [&](size_t bytes) { void* p = ws + off; off += (bytes + 255) & ~(size_t)255; return p; };
    unsigned short* xtb = (unsigned short*)alloc((size_t)B_ * N_ * C_ * 2);   // 8.4MB
    int*   cidx  = (int*)  alloc((size_t)4 * B_ * N_ * 4);
    int*   h     = (int*)  alloc((size_t)4 * B_ * N_ * 4);
    unsigned short* Mfrag = (unsigned short*)alloc((size_t)4 * 8 * 64 * 8 * 2);
    float* Wt    = (float*)alloc((size_t)4 * 9 * 4096 * 4);
    float* FWt   = (float*)alloc((size_t)4 * 4096 * 4);
    int*   emeta = (int*)  alloc((size_t)CAP * 4);
    float* ed    = (float*)alloc((size_t)CAP * 8 * 4);
    float* zcorr = (float*)alloc((size_t)CAP * 64 * 4);
    float* zbuf  = (float*)alloc((size_t)B_ * O_ * N_ * 4);                   // 16.8MB
    // contiguous zero-region: stats | cnt | flag  (single memset)
    float* stats = (float*)(ws + off); off += 1024;
    int*   cnt   = (int*)  (ws + off); off += 256;
    int*   flag  = (int*)  (ws + off); off += (size_t)4 * B_ * N_ * 4;

    hipMemsetAsync(stats, 0, 1024 + 256 + (size_t)4 * B_ * N_ * 4, stream);
    k_setup<<<1580, 256, 0, stream>>>(input, mc, indices, cw, fw,
                                      xtb, cidx, Mfrag, Wt, FWt, flag, emeta, ed, cnt);
    for (int s = 1; s < 4; ++s)
        k_compose<<<(B_ * N_) / 256, 256, 0, stream>>>(indices, cidx, s);
    k_hmap<<<(B_ * N_) / 256, 256, 0, stream>>>(reidx, cidx, h);
    k_corr<<<2048, 64, 0, stream>>>(xtb, cidx, Wt, FWt, emeta, ed, cnt, zcorr);
    k_fused<<<1024, 256, 0, stream>>>(xtb, h, flag, reidx, Mfrag, zcorr, fb, zbuf, stats);
    k_bnstats<<<1, 64, 0, stream>>>(stats, fb, gamma, beta, stats + 128);
    k_apply<<<4097, 256, 0, stream>>>(zbuf, fb, stats + 128, out);
}

// Round 4
// 78.541 us; speedup vs baseline: 5.0276x; 2.1790x over previous
//
#include <hip/hip_runtime.h>

#define K_ 9
#define SIGMA_INV 12.5f
#define EPS 1e-5f
#define B_ 4
#define C_ 64
#define O_ 64
#define N_ 16384
#define CAP 32768

typedef __attribute__((ext_vector_type(8))) short short8;
typedef __attribute__((ext_vector_type(4))) float f32x4;

__device__ __forceinline__ unsigned short f2bf(float f) {
    union { float f; unsigned u; } v; v.f = f;
    unsigned r = v.u + 0x7fffu + ((v.u >> 16) & 1u);   // round-nearest-even
    return (unsigned short)(r >> 16);
}
__device__ __forceinline__ float bf2f(unsigned short h) {
    union { unsigned u; float f; } v; v.u = ((unsigned)h) << 16;
    return v.f;
}
__device__ __forceinline__ void gload16(const void* g, void* l) {
    __builtin_amdgcn_global_load_lds((const __attribute__((address_space(1))) unsigned int*)g,
                                     (__attribute__((address_space(3))) unsigned int*)l,
                                     16, 0, 0);
}

// ---------------------------------------------------------------------------
// K_setup: heterogeneous roles.
//  [0,1024)      : transpose+bf16-convert tile (64n x 64c)
//  [1024,1280)   : scan (all 4 i at once via float4 mc reads)
//  [1280,1324)   : prep (4x M->Mfrag, 36x Wt, 4x FWt)
//  [1324,1580)   : compose step 0
// ---------------------------------------------------------------------------
__global__ __launch_bounds__(256) void k_setup(
    const float* __restrict__ in, const float* __restrict__ mc,
    const int* __restrict__ indices,
    const float* __restrict__ cw, const float* __restrict__ fw,
    unsigned short* __restrict__ xtb, int* __restrict__ cidx,
    unsigned short* __restrict__ Mfrag, float* __restrict__ Wt,
    float* __restrict__ FWt,
    int* __restrict__ flag, int* __restrict__ emeta,
    float* __restrict__ ed, int* __restrict__ cnt)
{
    int bid = blockIdx.x, t = threadIdx.x;
    if (bid < 1024) {                                    // ---- transpose + cvt
        __shared__ float tile[64][65];
        int b = bid & 3, n0 = (bid >> 2) * 64;
        for (int rep = 0; rep < 16; ++rep) {
            int idx = rep * 256 + t;
            int c = idx >> 6, j = idx & 63;
            tile[c][j] = in[((size_t)b * C_ + c) * N_ + n0 + j];
        }
        __syncthreads();
        for (int rep = 0; rep < 4; ++rep) {              // ushort4 packed writes
            int idx = rep * 256 + t;
            int j = idx >> 4, c4 = (idx & 15) * 4;
            ushort4 o;
            o.x = f2bf(tile[c4 + 0][j]); o.y = f2bf(tile[c4 + 1][j]);
            o.z = f2bf(tile[c4 + 2][j]); o.w = f2bf(tile[c4 + 3][j]);
            *(ushort4*)&xtb[((size_t)b * N_ + n0 + j) * 64 + c4] = o;
        }
    } else if (bid < 1280) {                             // ---- scan (4 i at once)
        __shared__ float cs[3][264][4];
        int sb = bid - 1024;
        int b = sb & 3, n0 = (sb >> 2) * 256;
        for (int idx = t; idx < 3 * 264; idx += 256) {
            int a = idx / 264, r = idx - a * 264;
            int m = n0 + r - 4;
            f32x4 v;
            if (m >= 0 && m < N_) v = *(const f32x4*)&mc[(((size_t)b * 3 + a) * N_ + m) * 4];
            else { v[0] = 1e9f; v[1] = 1e9f; v[2] = 1e9f; v[3] = 1e9f; }
            *(f32x4*)&cs[a][r][0] = v;
        }
        __syncthreads();
        int p = n0 + t;
        for (int i = 0; i < 4; ++i) {
            float c0 = cs[0][t + 4][i], c1 = cs[1][t + 4][i], c2 = cs[2][t + 4][i];
            float d[8]; bool any = false;
            #pragma unroll
            for (int kk = 0; kk < 8; ++kk) {
                int k = kk + (kk >= 4);
                float d0 = cs[0][t + k][i] - c0, d1 = cs[1][t + k][i] - c1,
                      d2 = cs[2][t + k][i] - c2;
                float dist = sqrtf(d0 * d0 + d1 * d1 + d2 * d2);
                float dd = 1.f - dist * SIGMA_INV;
                d[kk] = dd > 0.f ? dd : 0.f;
                any = any || (dd > 0.f);
            }
            if (any) {
                int e = atomicAdd(cnt, 1);
                if (e < CAP) {
                    emeta[e] = ((i * 4 + b) << 14) | p;
                    #pragma unroll
                    for (int kk = 0; kk < 8; ++kk) ed[(size_t)e * 8 + kk] = d[kk];
                    flag[(size_t)(i * 4 + b) * N_ + p] = e + 1;
                }
            }
        }
    } else if (bid < 1324) {                             // ---- prep
        int pb = bid - 1280;
        if (pb < 4) {
            __shared__ float w4[64][65];
            __shared__ float fws[64][65];
            int i = pb;
            for (int idx = t; idx < 4096; idx += 256) {
                int op = idx >> 6, c = idx & 63;
                w4[op][c]  = cw[(((size_t)(i * 64 + op)) * 64 + c) * 9 + 4];
                fws[op][c] = fw[(size_t)op * 256 + i * 64 + c];
            }
            __syncthreads();
            int o = t >> 2, cb = (t & 3) * 16;
            float acc[16];
            #pragma unroll
            for (int j = 0; j < 16; ++j) acc[j] = 0.f;
            for (int op = 0; op < 64; ++op) {
                float f = fws[o][op];
                #pragma unroll
                for (int j = 0; j < 16; ++j) acc[j] += f * w4[op][cb + j];
            }
            // emit MFMA A-fragment layout: Mfrag[w][s][lane][8]
            #pragma unroll
            for (int j = 0; j < 16; ++j) {
                int c = cb + j;
                int s = i * 2 + (c >> 5);
                int l = (((c >> 3) & 3) << 4) | (o & 15);
                int w_ = o >> 4;
                Mfrag[(((size_t)w_ * 8 + s) * 64 + l) * 8 + (c & 7)] = f2bf(acc[j]);
            }
        } else if (pb < 40) {
            int idx2 = pb - 4;
            int i = idx2 / 9, k = idx2 - i * 9;
            for (int idx = t; idx < 4096; idx += 256) {
                int c = idx >> 6, o = idx & 63;
                Wt[(size_t)(i * 9 + k) * 4096 + c * 64 + o] =
                    cw[(((size_t)(i * 64 + o)) * 64 + c) * 9 + k];
            }
        } else {
            int i = pb - 40;
            for (int idx = t; idx < 4096; idx += 256) {
                int c = idx >> 6, o = idx & 63;
                FWt[(size_t)(i * 64 + c) * 64 + o] = fw[(size_t)o * 256 + i * 64 + c];
            }
        }
    } else {                                             // ---- compose step 0
        int gid = (bid - 1324) * 256 + t;                // over B*N
        int b = gid >> 14, n = gid & (N_ - 1);
        cidx[(size_t)b * N_ + n] = indices[((size_t)b * N_ + n) * 4];
    }
}

// compose steps 1..3
__global__ void k_compose(const int* __restrict__ indices, int* __restrict__ cidx, int step) {
    int gid = blockIdx.x * blockDim.x + threadIdx.x;
    int b = gid >> 14, n = gid & (N_ - 1);
    int id = indices[((size_t)b * N_ + n) * 4 + step];
    cidx[(size_t)step * B_ * N_ + (size_t)b * N_ + n] =
        cidx[(size_t)(step - 1) * B_ * N_ + (size_t)b * N_ + id];
}

// h[i][b][n] = cidx[i][b][reidx[b][n][i]]
__global__ void k_hmap(const int* __restrict__ reidx, const int* __restrict__ cidx,
                       int* __restrict__ h) {
    int gid = blockIdx.x * 256 + threadIdx.x;
    int b = gid >> 14, n = gid & (N_ - 1);
    #pragma unroll
    for (int i = 0; i < 4; ++i) {
        int p = reidx[((size_t)b * N_ + n) * 4 + i];
        h[(size_t)(i * 4 + b) * N_ + n] = cidx[(size_t)(i * 4 + b) * N_ + p];
    }
}

// corrections: one wave per entry (grid-stride). zcorr[e][64] fp32.
__global__ __launch_bounds__(64) void k_corr(
    const unsigned short* __restrict__ xtb, const int* __restrict__ cidx,
    const float* __restrict__ Wt, const float* __restrict__ FWt,
    const int* __restrict__ emeta, const float* __restrict__ ed,
    const int* __restrict__ cnt, float* __restrict__ zcorr)
{
    __shared__ float xls[8][64];
    __shared__ float ycs[64];
    int t = threadIdx.x;
    int n = *cnt; if (n > CAP) n = CAP;
    for (int e = blockIdx.x; e < n; e += gridDim.x) {
        int meta = emeta[e];
        int ib = meta >> 14, p = meta & 16383;
        int i = ib >> 2, b = ib & 3;
        const int* ci = cidx + (size_t)ib * N_;
        float dd[8];
        #pragma unroll
        for (int kk = 0; kk < 8; ++kk) dd[kk] = ed[(size_t)e * 8 + kk];
        #pragma unroll
        for (int kk = 0; kk < 8; ++kk) {
            if (dd[kk] > 0.f) {
                int k = kk + (kk >= 4);
                int row = ci[p + k - 4];
                xls[kk][t] = bf2f(xtb[((size_t)b * N_ + row) * 64 + t]);
            }
        }
        __syncthreads();
        float y = 0.f;
        #pragma unroll 1
        for (int kk = 0; kk < 8; ++kk) {
            if (dd[kk] > 0.f) {
                int k = kk + (kk >= 4);
                const float* w = Wt + (size_t)(i * 9 + k) * 4096;
                float s0 = 0.f, s1 = 0.f, s2 = 0.f, s3 = 0.f;
                #pragma unroll
                for (int c = 0; c < 64; c += 4) {
                    s0 += w[(c + 0) * 64 + t] * xls[kk][c + 0];
                    s1 += w[(c + 1) * 64 + t] * xls[kk][c + 1];
                    s2 += w[(c + 2) * 64 + t] * xls[kk][c + 2];
                    s3 += w[(c + 3) * 64 + t] * xls[kk][c + 3];
                }
                y += dd[kk] * (((s0 + s1) + (s2 + s3)));
            }
        }
        ycs[t] = y;
        __syncthreads();
        const float* fwt = FWt + (size_t)i * 4096;
        float v0 = 0.f, v1 = 0.f, v2 = 0.f, v3 = 0.f;
        #pragma unroll
        for (int c = 0; c < 64; c += 4) {
            v0 += fwt[(c + 0) * 64 + t] * ycs[c + 0];
            v1 += fwt[(c + 1) * 64 + t] * ycs[c + 1];
            v2 += fwt[(c + 2) * 64 + t] * ycs[c + 2];
            v3 += fwt[(c + 3) * 64 + t] * ycs[c + 3];
        }
        zcorr[(size_t)e * 64 + t] = (v0 + v1) + (v2 + v3);
        __syncthreads();
    }
}

// ---------------------------------------------------------------------------
// k_fused: Z[64o x 64pos] = concat_i(M_i) [64x256] . stack_i(xg_i) [256x64]
// via mfma_f32_16x16x32_bf16. BN partials stored per-block (NO device atomics).
// ---------------------------------------------------------------------------
__global__ __launch_bounds__(256) void k_fused(
    const unsigned short* __restrict__ xtb, const int* __restrict__ h,
    const int* __restrict__ flag, const int* __restrict__ reidx,
    const unsigned short* __restrict__ Mfrag, const float* __restrict__ zcorr,
    const float* __restrict__ fb, float* __restrict__ zbuf,
    float* __restrict__ pstats)
{
    __shared__ __align__(16) unsigned short xg[256 * 64];   // [i*64+pos][c] bf16, chunk-swizzled
    __shared__ int fs[256];
    int bid = blockIdx.x;
    int b = (bid & 7) >> 1;                        // batch -> XCD pair (L2 locality)
    int nb = ((bid >> 3) << 1) | (bid & 1);
    int n0 = nb * 64;
    int t = threadIdx.x;
    int lane = t & 63, w = t >> 6;

    // gather indices for this wave's ordering i=w: direct global loads (no LDS, no barrier)
    int hvv[8];
    #pragma unroll
    for (int it = 0; it < 8; ++it)
        hvv[it] = h[(size_t)(w * 4 + b) * N_ + n0 + it * 8 + (lane >> 3)];
    // A-fragments (independent; fill the hvv-latency gap)
    short8 af[8];
    #pragma unroll
    for (int s = 0; s < 8; ++s)
        af[s] = *(const short8*)&Mfrag[(((size_t)w * 8 + s) * 64 + lane) * 8];
    // issue gathers: wave w stages ordering i=w (64 rows x 128B), 8 issues deep
    #pragma unroll
    for (int it = 0; it < 8; ++it) {
        int p = it * 8 + (lane >> 3);
        int cg = (lane & 7) ^ (p & 7);             // source-chunk swizzle
        const unsigned short* gp = xtb + ((size_t)b * N_ + hvv[it]) * 64 + cg * 8;
        gload16(gp, &xg[(size_t)(w * 64 + it * 8) * 64]);
    }
    // correction flags: 2-deep dependent chain overlapped with gather latency
    {
        int i = t >> 6, p = t & 63;
        int pr = reidx[((size_t)b * N_ + n0 + p) * 4 + i];
        fs[t] = flag[(size_t)(i * 4 + b) * N_ + pr];
    }
    asm volatile("s_waitcnt vmcnt(0)" ::: "memory");
    __syncthreads();

    // MFMA: 4 col-tiles x 8 K-steps
    f32x4 acc[4];
    #pragma unroll
    for (int ct = 0; ct < 4; ++ct) { acc[ct][0]=0.f; acc[ct][1]=0.f; acc[ct][2]=0.f; acc[ct][3]=0.f; }
    #pragma unroll
    for (int s = 0; s < 8; ++s) {
        int i2 = s >> 1;
        int cg = (s & 1) * 4 + (lane >> 4);
        #pragma unroll
        for (int ct = 0; ct < 4; ++ct) {
            int pos = ct * 16 + (lane & 15);
            const short8 bf = *(const short8*)((const char*)xg +
                ((size_t)(i2 * 64 + pos) * 128) + ((cg ^ (pos & 7)) * 16));
            acc[ct] = __builtin_amdgcn_mfma_f32_16x16x32_bf16(af[s], bf, acc[ct], 0, 0, 0);
        }
    }

    // epilogue: corrections + bias + store + per-block BN partials
    int og = w * 16 + (lane >> 4) * 4;             // lane's 4 output rows
    const f32x4 bias4 = *(const f32x4*)&fb[og];
    float sums[4] = {0.f, 0.f, 0.f, 0.f}, sqs[4] = {0.f, 0.f, 0.f, 0.f};
    #pragma unroll
    for (int ct = 0; ct < 4; ++ct) {
        int p = ct * 16 + (lane & 15);
        #pragma unroll
        for (int i = 0; i < 4; ++i) {
            int f = fs[i * 64 + p];
            if (f > 0) {
                const f32x4 vc = *(const f32x4*)&zcorr[(size_t)(f - 1) * 64 + og];
                acc[ct] += vc;
            }
        }
        f32x4 z = acc[ct] + bias4;
        int n = n0 + p;
        #pragma unroll
        for (int r = 0; r < 4; ++r) {
            zbuf[((size_t)b * O_ + og + r) * N_ + n] = z[r];
            sums[r] += z[r]; sqs[r] += z[r] * z[r];
        }
    }
    #pragma unroll
    for (int r = 0; r < 4; ++r) {
        float s = sums[r], q = sqs[r];
        for (int m = 8; m >= 1; m >>= 1) {
            s += __shfl_xor(s, m);
            q += __shfl_xor(q, m);
        }
        if ((lane & 15) == 0) {
            pstats[(size_t)(og + r) * 1024 + bid] = s;
            pstats[(size_t)(64 + og + r) * 1024 + bid] = q;
        }
    }
}

// 64 blocks, one per channel: coalesced reduction of pstats -> scale/shift
__global__ __launch_bounds__(256) void k_bnstats(
    const float* __restrict__ pstats, const float* __restrict__ fb,
    const float* __restrict__ gamma, const float* __restrict__ beta,
    float* __restrict__ sc)
{
    __shared__ float ls[4], lq[4];
    int o = blockIdx.x, t = threadIdx.x;
    int lane = t & 63, w = t >> 6;
    float s = 0.f, q = 0.f;
    #pragma unroll
    for (int r = 0; r < 4; ++r) {
        s += pstats[(size_t)o * 1024 + r * 256 + t];
        q += pstats[(size_t)(64 + o) * 1024 + r * 256 + t];
    }
    #pragma unroll
    for (int m = 32; m >= 1; m >>= 1) {
        s += __shfl_xor(s, m);
        q += __shfl_xor(q, m);
    }
    if (lane == 0) { ls[w] = s; lq[w] = q; }
    __syncthreads();
    if (t == 0) {
        s = ls[0] + ls[1] + ls[2] + ls[3];
        q = lq[0] + lq[1] + lq[2] + lq[3];
        float cnt = (float)(B_ * (N_ + 2));
        float bias = fb[o];
        s += 2.f * B_ * bias;
        q += 2.f * B_ * bias * bias;
        float mean = s / cnt;
        float var = q / cnt - mean * mean;
        float scale = gamma[o] / sqrtf(var + EPS);
        sc[o] = scale;
        sc[O_ + o] = beta[o] - mean * scale;
    }
}

// BN + ReLU -> out [B][O][N+2]; blocks [0,4096) interior (float4), block 4096 pads
__global__ __launch_bounds__(256) void k_apply(const float* __restrict__ zbuf,
                                               const float* __restrict__ fb,
                                               const float* __restrict__ sc,
                                               float* __restrict__ out) {
    int bid = blockIdx.x, t = threadIdx.x;
    if (bid < 4096) {
        int gid = bid * 256 + t;
        int row = gid >> 12;                       // (b*64+o), 4096 float4 per row
        int n = (gid & 4095) * 4;
        int o = row & 63;
        float scale = sc[o], shift = sc[O_ + o];
        f32x4 z = *(const f32x4*)&zbuf[(size_t)row * N_ + n];
        size_t ob = (size_t)row * (N_ + 2) + 1 + n;
        #pragma unroll
        for (int r = 0; r < 4; ++r)
            out[ob + r] = fmaxf(z[r] * scale + shift, 0.f);
    } else {
        int row = t;                               // 256 rows
        int o = row & 63;
        float v = fmaxf(fb[o] * sc[o] + sc[O_ + o], 0.f);
        out[(size_t)row * (N_ + 2)] = v;
        out[(size_t)row * (N_ + 2) + N_ + 1] = v;
    }
}

extern "C" void kernel_launch(void* const* d_in, const int* in_sizes, int n_in,
                              void* d_out, int out_size, void* d_ws, size_t ws_size,
                              hipStream_t stream) {
    const float* input   = (const float*)d_in[0];
    const float* mc      = (const float*)d_in[1];
    const int*   indices = (const int*)d_in[2];
    const int*   reidx   = (const int*)d_in[3];
    const float* cw      = (const float*)d_in[4];
    const float* fw      = (const float*)d_in[5];
    const float* fb      = (const float*)d_in[6];
    const float* gamma   = (const float*)d_in[7];
    const float* beta    = (const float*)d_in[8];
    float* out = (float*)d_out;

    char* ws = (char*)d_ws;
    size_t off = 0;
    auto alloc = [&](size_t bytes) { void* p = ws + off; off += (bytes + 255) & ~(size_t)255; return p; };
    unsigned short* xtb = (unsigned short*)alloc((size_t)B_ * N_ * C_ * 2);   // 8.4MB
    int*   cidx  = (int*)  alloc((size_t)4 * B_ * N_ * 4);
    int*   h     = (int*)  alloc((size_t)4 * B_ * N_ * 4);
    unsigned short* Mfrag = (unsigned short*)alloc((size_t)4 * 8 * 64 * 8 * 2);
    float* Wt    = (float*)alloc((size_t)4 * 9 * 4096 * 4);
    float* FWt   = (float*)alloc((size_t)4 * 4096 * 4);
    int*   emeta = (int*)  alloc((size_t)CAP * 4);
    float* ed    = (float*)alloc((size_t)CAP * 8 * 4);
    float* zcorr = (float*)alloc((size_t)CAP * 64 * 4);
    float* zbuf  = (float*)alloc((size_t)B_ * O_ * N_ * 4);                   // 16.8MB
    float* pstats= (float*)alloc((size_t)128 * 1024 * 4);                     // 512KB (no init needed)
    float* sc    = (float*)alloc((size_t)128 * 4);
    // contiguous zero-region: cnt | flag  (single memset)
    int*   cnt   = (int*)  (ws + off); off += 256;
    int*   flag  = (int*)  (ws + off); off += (size_t)4 * B_ * N_ * 4;

    hipMemsetAsync(cnt, 0, 256 + (size_t)4 * B_ * N_ * 4, stream);
    k_setup<<<1580, 256, 0, stream>>>(input, mc, indices, cw, fw,
                                      xtb, cidx, Mfrag, Wt, FWt, flag, emeta, ed, cnt);
    for (int s = 1; s < 4; ++s)
        k_compose<<<(B_ * N_) / 256, 256, 0, stream>>>(indices, cidx, s);
    k_hmap<<<(B_ * N_) / 256, 256, 0, stream>>>(reidx, cidx, h);
    k_corr<<<2048, 64, 0, stream>>>(xtb, cidx, Wt, FWt, emeta, ed, cnt, zcorr);
    k_fused<<<1024, 256, 0, stream>>>(xtb, h, flag, reidx, Mfrag, zcorr, fb, zbuf, pstats);
    k_bnstats<<<64, 256, 0, stream>>>(pstats, fb, gamma, beta, sc);
    k_apply<<<4097, 256, 0, stream>>>(zbuf, fb, sc, out);
}

// Round 5
// 69.113 us; speedup vs baseline: 5.7135x; 1.1364x over previous
//
#include <hip/hip_runtime.h>

#define K_ 9
#define SIGMA_INV 12.5f
#define EPS 1e-5f
#define B_ 4
#define C_ 64
#define O_ 64
#define N_ 16384
#define CAP 32768

typedef __attribute__((ext_vector_type(8))) short short8;
typedef __attribute__((ext_vector_type(4))) float f32x4;

__device__ __forceinline__ unsigned short f2bf(float f) {
    union { float f; unsigned u; } v; v.f = f;
    unsigned r = v.u + 0x7fffu + ((v.u >> 16) & 1u);   // round-nearest-even
    return (unsigned short)(r >> 16);
}
__device__ __forceinline__ float bf2f(unsigned short h) {
    union { unsigned u; float f; } v; v.u = ((unsigned)h) << 16;
    return v.f;
}
__device__ __forceinline__ void gload16(const void* g, void* l) {
    __builtin_amdgcn_global_load_lds((const __attribute__((address_space(1))) unsigned int*)g,
                                     (__attribute__((address_space(3))) unsigned int*)l,
                                     16, 0, 0);
}

// ---------------------------------------------------------------------------
// k_chain: h[i][b][n] = (idx_0 ∘ idx_1 ∘ … ∘ idx_i)(reidx[b][n][i]), direct
// pointer-chase (no materialized cidx). Also zeroes cnt (runs first in stream).
// ---------------------------------------------------------------------------
__global__ __launch_bounds__(256) void k_chain(const int* __restrict__ indices,
                                               const int* __restrict__ reidx,
                                               int* __restrict__ h,
                                               int* __restrict__ cnt) {
    int gid = blockIdx.x * 256 + threadIdx.x;
    if (gid == 0) *cnt = 0;
    int b = gid >> 14, n = gid & (N_ - 1);
    const int* ib = indices + (size_t)b * N_ * 4;
    const int4 r = *(const int4*)&reidx[((size_t)b * N_ + n) * 4];
    int t0 = ib[(size_t)r.x * 4 + 0];
    int t1 = ib[(size_t)r.y * 4 + 1];
    int t2 = ib[(size_t)r.z * 4 + 2];
    int t3 = ib[(size_t)r.w * 4 + 3];
    t1 = ib[(size_t)t1 * 4 + 0];
    t2 = ib[(size_t)t2 * 4 + 1];
    t3 = ib[(size_t)t3 * 4 + 2];
    t2 = ib[(size_t)t2 * 4 + 0];
    t3 = ib[(size_t)t3 * 4 + 1];
    t3 = ib[(size_t)t3 * 4 + 0];
    h[(size_t)(0 * 4 + b) * N_ + n] = t0;
    h[(size_t)(1 * 4 + b) * N_ + n] = t1;
    h[(size_t)(2 * 4 + b) * N_ + n] = t2;
    h[(size_t)(3 * 4 + b) * N_ + n] = t3;
}

// ---------------------------------------------------------------------------
// K_setup: heterogeneous roles.
//  [0,1024)      : transpose+bf16-convert tile (64n x 64c)
//  [1024,1280)   : scan (all 4 i at once; flag written UNCONDITIONALLY)
//  [1280,1324)   : prep (4x M->Mfrag, 36x Wt, 4x FWt)
// ---------------------------------------------------------------------------
__global__ __launch_bounds__(256) void k_setup(
    const float* __restrict__ in, const float* __restrict__ mc,
    const float* __restrict__ cw, const float* __restrict__ fw,
    unsigned short* __restrict__ xtb,
    unsigned short* __restrict__ Mfrag, float* __restrict__ Wt,
    float* __restrict__ FWt,
    int* __restrict__ flag, int* __restrict__ emeta,
    float* __restrict__ ed, int* __restrict__ cnt)
{
    int bid = blockIdx.x, t = threadIdx.x;
    if (bid < 1024) {                                    // ---- transpose + cvt
        __shared__ float tile[64][65];
        int b = bid & 3, n0 = (bid >> 2) * 64;
        for (int rep = 0; rep < 16; ++rep) {
            int idx = rep * 256 + t;
            int c = idx >> 6, j = idx & 63;
            tile[c][j] = in[((size_t)b * C_ + c) * N_ + n0 + j];
        }
        __syncthreads();
        for (int rep = 0; rep < 4; ++rep) {              // ushort4 packed writes
            int idx = rep * 256 + t;
            int j = idx >> 4, c4 = (idx & 15) * 4;
            ushort4 o;
            o.x = f2bf(tile[c4 + 0][j]); o.y = f2bf(tile[c4 + 1][j]);
            o.z = f2bf(tile[c4 + 2][j]); o.w = f2bf(tile[c4 + 3][j]);
            *(ushort4*)&xtb[((size_t)b * N_ + n0 + j) * 64 + c4] = o;
        }
    } else if (bid < 1280) {                             // ---- scan (4 i at once)
        __shared__ float cs[3][264][4];
        int sb = bid - 1024;
        int b = sb & 3, n0 = (sb >> 2) * 256;
        for (int idx = t; idx < 3 * 264; idx += 256) {
            int a = idx / 264, r = idx - a * 264;
            int m = n0 + r - 4;
            f32x4 v;
            if (m >= 0 && m < N_) v = *(const f32x4*)&mc[(((size_t)b * 3 + a) * N_ + m) * 4];
            else { v[0] = 1e9f; v[1] = 1e9f; v[2] = 1e9f; v[3] = 1e9f; }
            *(f32x4*)&cs[a][r][0] = v;
        }
        __syncthreads();
        int p = n0 + t;
        for (int i = 0; i < 4; ++i) {
            float c0 = cs[0][t + 4][i], c1 = cs[1][t + 4][i], c2 = cs[2][t + 4][i];
            float d[8]; bool any = false;
            #pragma unroll
            for (int kk = 0; kk < 8; ++kk) {
                int k = kk + (kk >= 4);
                float d0 = cs[0][t + k][i] - c0, d1 = cs[1][t + k][i] - c1,
                      d2 = cs[2][t + k][i] - c2;
                float dist = sqrtf(d0 * d0 + d1 * d1 + d2 * d2);
                float dd = 1.f - dist * SIGMA_INV;
                d[kk] = dd > 0.f ? dd : 0.f;
                any = any || (dd > 0.f);
            }
            int fv = 0;
            if (any) {
                int e = atomicAdd(cnt, 1);
                if (e < CAP) {
                    emeta[e] = ((i * 4 + b) << 14) | p;
                    #pragma unroll
                    for (int kk = 0; kk < 8; ++kk) ed[(size_t)e * 8 + kk] = d[kk];
                    fv = e + 1;
                }
            }
            flag[(size_t)(i * 4 + b) * N_ + p] = fv;     // unconditional: no memset needed
        }
    } else {                                             // ---- prep
        int pb = bid - 1280;
        if (pb < 4) {
            __shared__ float w4[64][65];
            __shared__ float fws[64][65];
            int i = pb;
            for (int idx = t; idx < 4096; idx += 256) {
                int op = idx >> 6, c = idx & 63;
                w4[op][c]  = cw[(((size_t)(i * 64 + op)) * 64 + c) * 9 + 4];
                fws[op][c] = fw[(size_t)op * 256 + i * 64 + c];
            }
            __syncthreads();
            int o = t >> 2, cb = (t & 3) * 16;
            float acc[16];
            #pragma unroll
            for (int j = 0; j < 16; ++j) acc[j] = 0.f;
            for (int op = 0; op < 64; ++op) {
                float f = fws[o][op];
                #pragma unroll
                for (int j = 0; j < 16; ++j) acc[j] += f * w4[op][cb + j];
            }
            // emit MFMA A-fragment layout: Mfrag[w][s][lane][8]
            #pragma unroll
            for (int j = 0; j < 16; ++j) {
                int c = cb + j;
                int s = i * 2 + (c >> 5);
                int l = (((c >> 3) & 3) << 4) | (o & 15);
                int w_ = o >> 4;
                Mfrag[(((size_t)w_ * 8 + s) * 64 + l) * 8 + (c & 7)] = f2bf(acc[j]);
            }
        } else if (pb < 40) {
            int idx2 = pb - 4;
            int i = idx2 / 9, k = idx2 - i * 9;
            for (int idx = t; idx < 4096; idx += 256) {
                int c = idx >> 6, o = idx & 63;
                Wt[(size_t)(i * 9 + k) * 4096 + c * 64 + o] =
                    cw[(((size_t)(i * 64 + o)) * 64 + c) * 9 + k];
            }
        } else {
            int i = pb - 40;
            for (int idx = t; idx < 4096; idx += 256) {
                int c = idx >> 6, o = idx & 63;
                FWt[(size_t)(i * 64 + c) * 64 + o] = fw[(size_t)o * 256 + i * 64 + c];
            }
        }
    }
}

// corrections: one wave per entry (grid-stride); tap rows pointer-chased in
// parallel lanes (depth <= i+1 <= 4+1). zcorr[e][64] fp32.
__global__ __launch_bounds__(64) void k_corr(
    const unsigned short* __restrict__ xtb, const int* __restrict__ indices,
    const float* __restrict__ Wt, const float* __restrict__ FWt,
    const int* __restrict__ emeta, const float* __restrict__ ed,
    const int* __restrict__ cnt, float* __restrict__ zcorr)
{
    __shared__ float xls[8][64];
    __shared__ float ycs[64];
    __shared__ int rows_s[8];
    int t = threadIdx.x;
    int n = *cnt; if (n > CAP) n = CAP;
    for (int e = blockIdx.x; e < n; e += gridDim.x) {
        int meta = emeta[e];
        int ibx = meta >> 14, p = meta & 16383;
        int i = ibx >> 2, b = ibx & 3;
        const int* idxb = indices + (size_t)b * N_ * 4;
        float dd[8];
        #pragma unroll
        for (int kk = 0; kk < 8; ++kk) dd[kk] = ed[(size_t)e * 8 + kk];
        if (t < 8) {                         // lane t chases tap t's row
            int row = 0;
            if (dd[t] > 0.f) {
                int k = t + (t >= 4);
                int rr = p + k - 4;          // in-bounds guaranteed when dd>0
                for (int s = i; s >= 0; --s) rr = idxb[(size_t)rr * 4 + s];
                row = rr;
            }
            rows_s[t] = row;
        }
        __syncthreads();
        #pragma unroll
        for (int kk = 0; kk < 8; ++kk) {
            if (dd[kk] > 0.f)
                xls[kk][t] = bf2f(xtb[((size_t)b * N_ + rows_s[kk]) * 64 + t]);
        }
        __syncthreads();
        float y = 0.f;
        #pragma unroll 1
        for (int kk = 0; kk < 8; ++kk) {
            if (dd[kk] > 0.f) {
                int k = kk + (kk >= 4);
                const float* w = Wt + (size_t)(i * 9 + k) * 4096;
                float s0 = 0.f, s1 = 0.f, s2 = 0.f, s3 = 0.f;
                #pragma unroll
                for (int c = 0; c < 64; c += 4) {
                    s0 += w[(c + 0) * 64 + t] * xls[kk][c + 0];
                    s1 += w[(c + 1) * 64 + t] * xls[kk][c + 1];
                    s2 += w[(c + 2) * 64 + t] * xls[kk][c + 2];
                    s3 += w[(c + 3) * 64 + t] * xls[kk][c + 3];
                }
                y += dd[kk] * (((s0 + s1) + (s2 + s3)));
            }
        }
        ycs[t] = y;
        __syncthreads();
        const float* fwt = FWt + (size_t)i * 4096;
        float v0 = 0.f, v1 = 0.f, v2 = 0.f, v3 = 0.f;
        #pragma unroll
        for (int c = 0; c < 64; c += 4) {
            v0 += fwt[(c + 0) * 64 + t] * ycs[c + 0];
            v1 += fwt[(c + 1) * 64 + t] * ycs[c + 1];
            v2 += fwt[(c + 2) * 64 + t] * ycs[c + 2];
            v3 += fwt[(c + 3) * 64 + t] * ycs[c + 3];
        }
        zcorr[(size_t)e * 64 + t] = (v0 + v1) + (v2 + v3);
        __syncthreads();
    }
}

// ---------------------------------------------------------------------------
// k_fused: Z[64o x 64pos] = concat_i(M_i) [64x256] . stack_i(xg_i) [256x64]
// via mfma_f32_16x16x32_bf16. BN partials stored per-block (NO device atomics).
// ---------------------------------------------------------------------------
__global__ __launch_bounds__(256) void k_fused(
    const unsigned short* __restrict__ xtb, const int* __restrict__ h,
    const int* __restrict__ flag, const int* __restrict__ reidx,
    const unsigned short* __restrict__ Mfrag, const float* __restrict__ zcorr,
    const float* __restrict__ fb, float* __restrict__ zbuf,
    float* __restrict__ pstats)
{
    __shared__ __align__(16) unsigned short xg[256 * 64];   // [i*64+pos][c] bf16, chunk-swizzled
    __shared__ int fs[256];
    int bid = blockIdx.x;
    int b = (bid & 7) >> 1;                        // batch -> XCD pair (L2 locality)
    int nb = ((bid >> 3) << 1) | (bid & 1);
    int n0 = nb * 64;
    int t = threadIdx.x;
    int lane = t & 63, w = t >> 6;

    // gather indices for this wave's ordering i=w: direct global loads
    int hvv[8];
    #pragma unroll
    for (int it = 0; it < 8; ++it)
        hvv[it] = h[(size_t)(w * 4 + b) * N_ + n0 + it * 8 + (lane >> 3)];
    // A-fragments (independent; fill the hvv-latency gap)
    short8 af[8];
    #pragma unroll
    for (int s = 0; s < 8; ++s)
        af[s] = *(const short8*)&Mfrag[(((size_t)w * 8 + s) * 64 + lane) * 8];
    // issue gathers: wave w stages ordering i=w (64 rows x 128B), 8 issues deep
    #pragma unroll
    for (int it = 0; it < 8; ++it) {
        int p = it * 8 + (lane >> 3);
        int cg = (lane & 7) ^ (p & 7);             // source-chunk swizzle
        const unsigned short* gp = xtb + ((size_t)b * N_ + hvv[it]) * 64 + cg * 8;
        gload16(gp, &xg[(size_t)(w * 64 + it * 8) * 64]);
    }
    // correction flags: 2-deep dependent chain overlapped with gather latency
    {
        int i = t >> 6, p = t & 63;
        int pr = reidx[((size_t)b * N_ + n0 + p) * 4 + i];
        fs[t] = flag[(size_t)(i * 4 + b) * N_ + pr];
    }
    asm volatile("s_waitcnt vmcnt(0)" ::: "memory");
    __syncthreads();

    // MFMA: 4 col-tiles x 8 K-steps
    f32x4 acc[4];
    #pragma unroll
    for (int ct = 0; ct < 4; ++ct) { acc[ct][0]=0.f; acc[ct][1]=0.f; acc[ct][2]=0.f; acc[ct][3]=0.f; }
    #pragma unroll
    for (int s = 0; s < 8; ++s) {
        int i2 = s >> 1;
        int cg = (s & 1) * 4 + (lane >> 4);
        #pragma unroll
        for (int ct = 0; ct < 4; ++ct) {
            int pos = ct * 16 + (lane & 15);
            const short8 bf = *(const short8*)((const char*)xg +
                ((size_t)(i2 * 64 + pos) * 128) + ((cg ^ (pos & 7)) * 16));
            acc[ct] = __builtin_amdgcn_mfma_f32_16x16x32_bf16(af[s], bf, acc[ct], 0, 0, 0);
        }
    }

    // epilogue: corrections + bias + store + per-block BN partials
    int og = w * 16 + (lane >> 4) * 4;             // lane's 4 output rows
    const f32x4 bias4 = *(const f32x4*)&fb[og];
    float sums[4] = {0.f, 0.f, 0.f, 0.f}, sqs[4] = {0.f, 0.f, 0.f, 0.f};
    #pragma unroll
    for (int ct = 0; ct < 4; ++ct) {
        int p = ct * 16 + (lane & 15);
        #pragma unroll
        for (int i = 0; i < 4; ++i) {
            int f = fs[i * 64 + p];
            if (f > 0) {
                const f32x4 vc = *(const f32x4*)&zcorr[(size_t)(f - 1) * 64 + og];
                acc[ct] += vc;
            }
        }
        f32x4 z = acc[ct] + bias4;
        int n = n0 + p;
        #pragma unroll
        for (int r = 0; r < 4; ++r) {
            zbuf[((size_t)b * O_ + og + r) * N_ + n] = z[r];
            sums[r] += z[r]; sqs[r] += z[r] * z[r];
        }
    }
    #pragma unroll
    for (int r = 0; r < 4; ++r) {
        float s = sums[r], q = sqs[r];
        for (int m = 8; m >= 1; m >>= 1) {
            s += __shfl_xor(s, m);
            q += __shfl_xor(q, m);
        }
        if ((lane & 15) == 0) {
            pstats[(size_t)(og + r) * 1024 + bid] = s;
            pstats[(size_t)(64 + og + r) * 1024 + bid] = q;
        }
    }
}

// 64 blocks, one per channel: coalesced reduction of pstats -> scale/shift
__global__ __launch_bounds__(256) void k_bnstats(
    const float* __restrict__ pstats, const float* __restrict__ fb,
    const float* __restrict__ gamma, const float* __restrict__ beta,
    float* __restrict__ sc)
{
    __shared__ float ls[4], lq[4];
    int o = blockIdx.x, t = threadIdx.x;
    int lane = t & 63, w = t >> 6;
    float s = 0.f, q = 0.f;
    #pragma unroll
    for (int r = 0; r < 4; ++r) {
        s += pstats[(size_t)o * 1024 + r * 256 + t];
        q += pstats[(size_t)(64 + o) * 1024 + r * 256 + t];
    }
    #pragma unroll
    for (int m = 32; m >= 1; m >>= 1) {
        s += __shfl_xor(s, m);
        q += __shfl_xor(q, m);
    }
    if (lane == 0) { ls[w] = s; lq[w] = q; }
    __syncthreads();
    if (t == 0) {
        s = ls[0] + ls[1] + ls[2] + ls[3];
        q = lq[0] + lq[1] + lq[2] + lq[3];
        float cnt = (float)(B_ * (N_ + 2));
        float bias = fb[o];
        s += 2.f * B_ * bias;
        q += 2.f * B_ * bias * bias;
        float mean = s / cnt;
        float var = q / cnt - mean * mean;
        float scale = gamma[o] / sqrtf(var + EPS);
        sc[o] = scale;
        sc[O_ + o] = beta[o] - mean * scale;
    }
}

// BN + ReLU -> out [B][O][N+2]; blocks [0,4096) interior (float4), block 4096 pads
__global__ __launch_bounds__(256) void k_apply(const float* __restrict__ zbuf,
                                               const float* __restrict__ fb,
                                               const float* __restrict__ sc,
                                               float* __restrict__ out) {
    int bid = blockIdx.x, t = threadIdx.x;
    if (bid < 4096) {
        int gid = bid * 256 + t;
        int row = gid >> 12;                       // (b*64+o), 4096 float4 per row
        int n = (gid & 4095) * 4;
        int o = row & 63;
        float scale = sc[o], shift = sc[O_ + o];
        f32x4 z = *(const f32x4*)&zbuf[(size_t)row * N_ + n];
        size_t ob = (size_t)row * (N_ + 2) + 1 + n;
        #pragma unroll
        for (int r = 0; r < 4; ++r)
            out[ob + r] = fmaxf(z[r] * scale + shift, 0.f);
    } else {
        int row = t;                               // 256 rows
        int o = row & 63;
        float v = fmaxf(fb[o] * sc[o] + sc[O_ + o], 0.f);
        out[(size_t)row * (N_ + 2)] = v;
        out[(size_t)row * (N_ + 2) + N_ + 1] = v;
    }
}

extern "C" void kernel_launch(void* const* d_in, const int* in_sizes, int n_in,
                              void* d_out, int out_size, void* d_ws, size_t ws_size,
                              hipStream_t stream) {
    const float* input   = (const float*)d_in[0];
    const float* mc      = (const float*)d_in[1];
    const int*   indices = (const int*)d_in[2];
    const int*   reidx   = (const int*)d_in[3];
    const float* cw      = (const float*)d_in[4];
    const float* fw      = (const float*)d_in[5];
    const float* fb      = (const float*)d_in[6];
    const float* gamma   = (const float*)d_in[7];
    const float* beta    = (const float*)d_in[8];
    float* out = (float*)d_out;

    char* ws = (char*)d_ws;
    size_t off = 0;
    auto alloc = [&](size_t bytes) { void* p = ws + off; off += (bytes + 255) & ~(size_t)255; return p; };
    unsigned short* xtb = (unsigned short*)alloc((size_t)B_ * N_ * C_ * 2);   // 8.4MB
    int*   h     = (int*)  alloc((size_t)4 * B_ * N_ * 4);
    unsigned short* Mfrag = (unsigned short*)alloc((size_t)4 * 8 * 64 * 8 * 2);
    float* Wt    = (float*)alloc((size_t)4 * 9 * 4096 * 4);
    float* FWt   = (float*)alloc((size_t)4 * 4096 * 4);
    int*   emeta = (int*)  alloc((size_t)CAP * 4);
    float* ed    = (float*)alloc((size_t)CAP * 8 * 4);
    float* zcorr = (float*)alloc((size_t)CAP * 64 * 4);
    float* zbuf  = (float*)alloc((size_t)B_ * O_ * N_ * 4);                   // 16.8MB
    float* pstats= (float*)alloc((size_t)128 * 1024 * 4);                     // 512KB
    float* sc    = (float*)alloc((size_t)128 * 4);
    int*   flag  = (int*)  alloc((size_t)4 * B_ * N_ * 4);                    // written unconditionally
    int*   cnt   = (int*)  alloc(256);

    k_chain<<<256, 256, 0, stream>>>(indices, reidx, h, cnt);                 // also zeroes cnt
    k_setup<<<1324, 256, 0, stream>>>(input, mc, cw, fw,
                                      xtb, Mfrag, Wt, FWt, flag, emeta, ed, cnt);
    k_corr<<<2048, 64, 0, stream>>>(xtb, indices, Wt, FWt, emeta, ed, cnt, zcorr);
    k_fused<<<1024, 256, 0, stream>>>(xtb, h, flag, reidx, Mfrag, zcorr, fb, zbuf, pstats);
    k_bnstats<<<64, 256, 0, stream>>>(pstats, fb, gamma, beta, sc);
    k_apply<<<4097, 256, 0, stream>>>(zbuf, fb, sc, out);
}